// Round 5
// baseline (272.987 us; speedup 1.0000x reference)
//
#include <hip/hip_runtime.h>

// LSTM(H=5, in=1), T=2048, B=8192, + ReLU + FC head.
// Round 13: R11 exact (R12's tree/DPP reorder regressed +2.5us — this
// kernel is schedule-order-sensitive and the compiler follows source
// order) + one dependence-graph fix the compiler wasn't making:
//  - uo/Ao hoisted OUT of the uf->P->D->R critical segment (uo is a
//    16-issue-cy trans consumed only by Den at step end). It now fills
//    the R=frcp(D) latency window with t2vM/N/base02. Pure independent-
//    op reordering: no FP reassociation, bitwise-identical output.
//  - base13 moved into the wm=exp2(c2) latency window (was after h,
//    covering the h->DPP hazard; compiler nops cover that for ~2cy).
// Model: 249 cy/step = 202 issue + 47 tail stall; this targets ~16cy of
// the tail. Trees h0-rooted, DPP t04-first = R11's proven order.
// Structure (fixed since R6): 8 lanes/elem, 1024 waves = 1/SIMD, hw
// exp2/rcp, packed (i,g)/(f,o) matvec, scaled cell state c2=c*(-2log2e).

#define TLEN 2048

typedef float v2f __attribute__((ext_vector_type(2)));

__device__ __forceinline__ float fexp2(float v) { return __builtin_amdgcn_exp2f(v); }
__device__ __forceinline__ float frcp(float v)  { return __builtin_amdgcn_rcpf(v); }
__device__ __forceinline__ v2f fma2(v2f a, v2f b, v2f c) {
    return __builtin_elementwise_fma(a, b, c);
}

template<int CTRL>
__device__ __forceinline__ float dppmov(float v) {
    return __int_as_float(__builtin_amdgcn_mov_dpp(__float_as_int(v), CTRL, 0xF, 0xF, true));
}
template<int CTRL, int BANK_MASK>
__device__ __forceinline__ float dppupd(float old, float v) {
    return __int_as_float(__builtin_amdgcn_update_dpp(
        __float_as_int(old), __float_as_int(v), CTRL, 0xF, BANK_MASK, false));
}

__global__ __launch_bounds__(256, 1) void lstm_fused8t(
    const float* __restrict__ x,      // [B, T, 1]
    const float* __restrict__ W_ih,   // [20, 1]
    const float* __restrict__ W_hh,   // [20, 5]
    const float* __restrict__ b_ih,   // [20]
    const float* __restrict__ b_hh,   // [20]
    const float* __restrict__ W_fc,   // [1, 5]
    const float* __restrict__ b_fc,   // [1]
    float* __restrict__ out, int B)
{
    const int tid = blockIdx.x * 256 + threadIdx.x;
    const int b = tid >> 3;
    const int lane8 = tid & 7;
    // Lanes 5-7 duplicate units 1-3 so the upper quad holds {h4,h1,h2,h3}:
    // quad_perm(m) broadcasts h_m to both quads in one DPP for m=1,2,3.
    const int k = lane8 < 5 ? lane8 : lane8 - 4;

    constexpr float L2E   = 1.4426950408889634f;
    constexpr float P2L2E = 2.8853900817779268f;   // +2*log2e
    constexpr float M2L2E = -2.8853900817779268f;  // -2*log2e

    // Packed per-lane weights: pair02 = (i-row, g-row), pair13 = (f-row, o-row)
    v2f wih02, wih13, bias02, bias13, whh02[5], whh13[5];
    {
        const int ri = k, rf = 5 + k, rg = 10 + k, ro = 15 + k;
        wih02  = v2f{W_ih[ri] * -L2E,               W_ih[rg] * M2L2E};
        wih13  = v2f{W_ih[rf] * -L2E,               W_ih[ro] * -L2E};
        bias02 = v2f{(b_ih[ri] + b_hh[ri]) * -L2E,  (b_ih[rg] + b_hh[rg]) * M2L2E};
        bias13 = v2f{(b_ih[rf] + b_hh[rf]) * -L2E,  (b_ih[ro] + b_hh[ro]) * -L2E};
#pragma unroll
        for (int m = 0; m < 5; ++m) {
            whh02[m] = v2f{W_hh[ri * 5 + m] * -L2E,  W_hh[rg * 5 + m] * M2L2E};
            whh13[m] = v2f{W_hh[rf * 5 + m] * -L2E,  W_hh[ro * 5 + m] * -L2E};
        }
    }

    float c2 = 0.0f;   // scaled cell state: c * (-2*log2e)
    float h0v = 0.0f, h1v = 0.0f, h2v = 0.0f, h3v = 0.0f, h4v = 0.0f;

    const float4* xp = reinterpret_cast<const float4*>(x + (size_t)b * TLEN);
    float4 xa = xp[0], xb = xp[1], xc = xp[2], xd = xp[3];
    // h-independent base for step 0
    v2f base02 = fma2(v2f{xa.x, xa.x}, wih02, bias02);
    v2f base13 = fma2(v2f{xa.x, xa.x}, wih13, bias13);

    // 16-step body: S0..S3 = this half's four float4s, NEXT0 = next block's
    // first x (feeds the base for the step after this block's last).
#define STEP16(S0, S1, S2, S3, NEXT0) do {                                    \
    float xs[16] = {S0.y, S0.z, S0.w, S1.x, S1.y, S1.z, S1.w, S2.x,           \
                    S2.y, S2.z, S2.w, S3.x, S3.y, S3.z, S3.w, (NEXT0)};       \
    _Pragma("unroll")                                                         \
    for (int q = 0; q < 16; ++q) {                                            \
        const v2f h0s = v2f{h0v, h0v}, h1s = v2f{h1v, h1v}, h2s = v2f{h2v, h2v}; \
        const v2f h3s = v2f{h3v, h3v}, h4s = v2f{h4v, h4v};                   \
        v2f za02 = fma2(h0s, whh02[0], base02);                               \
        za02 = fma2(h1s, whh02[1], za02);                                     \
        v2f zb02 = fma2(h3s, whh02[3], h2s * whh02[2]);                       \
        zb02 = fma2(h4s, whh02[4], zb02);                                     \
        const v2f z02 = za02 + zb02;         /* (zi*-L2E, zg*-2L2E) */        \
        v2f za13 = fma2(h0s, whh13[0], base13);                               \
        za13 = fma2(h1s, whh13[1], za13);                                     \
        v2f zb13 = fma2(h3s, whh13[3], h2s * whh13[2]);                       \
        zb13 = fma2(h4s, whh13[4], zb13);                                     \
        const v2f z13 = za13 + zb13;         /* (zf*-L2E, zo*-L2E) */         \
        /* c-path trans only: uo is NOT needed until Den — keep it out of   */\
        /* the uf->P->D->R critical segment (saves 16 issue cy on the path) */\
        const float ui = fexp2(z02.x);       /* e^{-zi}  */                   \
        const float ug = fexp2(z02.y);       /* e^{-2zg} */                   \
        const float uf = fexp2(z13.x);       /* e^{-zf}  */                   \
        const float Ag = 1.0f + ug;                                           \
        const float Af = 1.0f + uf;                                           \
        const float P  = fmaf(ui, Ag, Ag);   /* (1+ui)(1+ug) */               \
        const float D  = P * Af;                                              \
        const float R  = frcp(D);                                             \
        /* R-latency window fill: uo, Ao, t2vM, N, next-step base02 */        \
        const float uo = fexp2(z13.y);       /* e^{-zo}  */                   \
        const float Ao = 1.0f + uo;                                           \
        const float t2vM = fmaf(ug, P2L2E, M2L2E) * Af;  /* (1-ug)*M2L2E*Af */\
        const float N  = fmaf(P, c2, t2vM);                                   \
        const float xn = xs[q];                                               \
        base02 = fma2(v2f{xn, xn}, wih02, bias02);                            \
        c2 = N * R;                          /* scaled cell state */          \
        const float wm = fexp2(c2);          /* e^{-2c} */                    \
        /* wm-latency window fill: next-step base13 */                        \
        base13 = fma2(v2f{xn, xn}, wih13, bias13);                            \
        const float Den = fmaf(Ao, wm, Ao);  /* Ao*(1+wm) */                  \
        const float Ro = frcp(Den);                                           \
        const float h  = fmaf(-wm, Ro, Ro);  /* (1-wm)*Ro = o*tanh(c) */      \
        /* DPP broadcast (R11 proven order): t04 first, 3 single-mov        */\
        /* broadcasts fill its hazard window, dependent updates last.       */\
        const float t04 = dppmov<0x00>(h);   /* lower=h0, upper=h4 */         \
        h1v = dppmov<0x55>(h);               /* both quads <- h1 */           \
        h2v = dppmov<0xAA>(h);               /* both quads <- h2 */           \
        h3v = dppmov<0xFF>(h);               /* both quads <- h3 */           \
        h0v = dppupd<0x114, 0xA>(t04, t04);  /* row_shl:4, upper <- h0 */     \
        h4v = dppupd<0x104, 0x5>(t04, t04);  /* row_shr:4, lower <- h4 */     \
    } } while (0)

#pragma unroll 1
    for (int t32 = 0; t32 < TLEN / 32; ++t32) {
        // half A: consume xa..xd; prefetch B-set (always in range)
        const int ib = 8 * t32 + 4;
        float4 ya = xp[ib], yb = xp[ib + 1], yc = xp[ib + 2], yd = xp[ib + 3];
        STEP16(xa, xb, xc, xd, ya.x);
        // half B: consume ya..yd; prefetch next A-set (clamped dummy at end)
        const int ia = (t32 + 1 < TLEN / 32) ? 8 * t32 + 8 : 0;
        xa = xp[ia]; xb = xp[ia + 1]; xc = xp[ia + 2]; xd = xp[ia + 3];
        STEP16(ya, yb, yc, yd, xa.x);
    }
#undef STEP16

    if (lane8 == 0) {
        float acc = b_fc[0];
        acc = fmaf(fmaxf(h0v, 0.0f), W_fc[0], acc);
        acc = fmaf(fmaxf(h1v, 0.0f), W_fc[1], acc);
        acc = fmaf(fmaxf(h2v, 0.0f), W_fc[2], acc);
        acc = fmaf(fmaxf(h3v, 0.0f), W_fc[3], acc);
        acc = fmaf(fmaxf(h4v, 0.0f), W_fc[4], acc);
        out[b] = acc;
    }
}

extern "C" void kernel_launch(void* const* d_in, const int* in_sizes, int n_in,
                              void* d_out, int out_size, void* d_ws, size_t ws_size,
                              hipStream_t stream) {
    const float* x    = (const float*)d_in[0];
    const float* W_ih = (const float*)d_in[1];
    const float* W_hh = (const float*)d_in[2];
    const float* b_ih = (const float*)d_in[3];
    const float* b_hh = (const float*)d_in[4];
    const float* W_fc = (const float*)d_in[5];
    const float* b_fc = (const float*)d_in[6];
    float* out = (float*)d_out;
    const int B = out_size;  // 8192
    const int threads = B * 8;  // 65536 = 1024 waves = 1/SIMD
    lstm_fused8t<<<threads / 256, 256, 0, stream>>>(
        x, W_ih, W_hh, b_ih, b_hh, W_fc, b_fc, out, B);
}